// Round 3
// baseline (573.423 us; speedup 1.0000x reference)
//
#include <hip/hip_runtime.h>
#include <hip/hip_bf16.h>
#include <math.h>

#define C_NUM 345
#define CP    384   // padded class count (3 x 128, 24 x 16)
#define A_DIM 512
#define N_NUM 128
#define KB    64    // b-slice (GEMM K) per block
#define NBB   8     // blocks along b

typedef short bf16x8 __attribute__((ext_vector_type(8)));
typedef float f32x4  __attribute__((ext_vector_type(4)));

__device__ __forceinline__ short f2bf(float f) {
    unsigned u = __builtin_bit_cast(unsigned, f);
    u += 0x7fffu + ((u >> 16) & 1u);   // RNE
    return (short)(u >> 16);
}

// XOR-swizzled index (in shorts) for a 64-col bf16 tile (128 B rows, 8
// 16B-chunks/row). Chunk column xored with row&7 -> frag ds_read_b128 and
// staging ds_write land at <=2-way (free) / 4-way (writes) conflicts.
__device__ __forceinline__ int swz64(int r, int k) {
    return r * 64 + ((((k >> 3) ^ (r & 7)) << 3) | (k & 7));
}

// q2[n,c] += v[c,:]^T Sigma_l[:, bslice] v[c, bslice],  v = w_c - w_l.
// MFMA: u[a,c] = sum_b Sa[a,b] * Vb[c,b]; epilogue: qp[c] += u[a,c]*v[c,a].
// V staged ONCE per block; Sigma tiles double-buffered so HBM fetch of the
// compulsory 128 MB overlaps MFMA (round-2 was fetch-duty-cycle bound).
__global__ __launch_bounds__(256, 2) void qkern(
    const float* __restrict__ W,      // [C, A]
    const int*   __restrict__ labels, // [N]
    const float* __restrict__ cov,    // [C, A, A]
    float*       __restrict__ q2)     // [N, C] accumulator (zeroed)
{
    const int bb = blockIdx.x;        // 0..7  b-slice
    const int n  = blockIdx.y;        // 0..127
    const int b0 = bb * KB;
    const int l  = labels[n];
    const float* __restrict__ Sg = cov + (size_t)l * A_DIM * A_DIM;
    const float* __restrict__ Wl = W + (size_t)l * A_DIM;

    __shared__ short Vb[CP * KB];      // 48 KB: rows c, cols b
    __shared__ short Sa[2][64 * KB];   // 2 x 8 KB: rows a (64-chunk), cols b

    const int tid  = threadIdx.x;
    const int lane = tid & 63;
    const int w    = tid >> 6;        // wave 0..3 -> c-range [96w, 96w+96)
    const int l15  = lane & 15;
    const int g    = lane >> 4;       // 0..3

    // staging coords: 16 threads per row (float4 each)
    const int c4 = tid & 15;
    const int r0 = tid >> 4;          // 0..15

    // ---- prefetch Sigma tile at=0 (in flight during V staging) ----
    float4 pf[4];
    {
        const float* sp = Sg + b0 + c4 * 4;
#pragma unroll
        for (int p = 0; p < 4; p++)
            pf[p] = *(const float4*)(sp + (size_t)(r0 + p * 16) * A_DIM);
    }

    // ---- stage V once: Vb[c][b] = bf16(W[c][b0+b] - Wl[b0+b]) ----
    const float4 wl4 = *(const float4*)(Wl + b0 + c4 * 4);
#pragma unroll
    for (int p = 0; p < 24; p++) {
        const int r = r0 + p * 16;    // 0..383
        short4 h = make_short4(0, 0, 0, 0);
        if (r < C_NUM) {
            const float4 wv = *(const float4*)(W + (size_t)r * A_DIM + b0 + c4 * 4);
            h = make_short4(f2bf(wv.x - wl4.x), f2bf(wv.y - wl4.y),
                            f2bf(wv.z - wl4.z), f2bf(wv.w - wl4.w));
        }
        *(short4*)(&Vb[swz64(r, c4 * 4)]) = h;
    }
    // ---- write Sigma tile 0 into buffer 0 ----
#pragma unroll
    for (int p = 0; p < 4; p++) {
        const float4 s = pf[p];
        *(short4*)(&Sa[0][swz64(r0 + p * 16, c4 * 4)]) =
            make_short4(f2bf(s.x), f2bf(s.y), f2bf(s.z), f2bf(s.w));
    }
    __syncthreads();

    float qp[6] = {0.f, 0.f, 0.f, 0.f, 0.f, 0.f};

    for (int at = 0; at < 8; at++) {
        // issue next Sigma tile's loads NOW; they fly during MFMA+epilogue
        if (at < 7) {
            const float* sp = Sg + (size_t)(at + 1) * 64 * A_DIM + b0 + c4 * 4;
#pragma unroll
            for (int p = 0; p < 4; p++)
                pf[p] = *(const float4*)(sp + (size_t)(r0 + p * 16) * A_DIM);
        }

        // ---- MFMA: u[a 0..63][c-range of wave] over K=64 ----
        f32x4 acc[4][6];
#pragma unroll
        for (int i = 0; i < 4; i++)
#pragma unroll
            for (int j = 0; j < 6; j++) {
                f32x4 z = {0.f, 0.f, 0.f, 0.f};
                acc[i][j] = z;
            }
        const short* buf = Sa[at & 1];
#pragma unroll
        for (int kt = 0; kt < 2; kt++) {
            const int kb = kt * 32 + g * 8;   // frag: k = quad*8 + j
            bf16x8 af[4], bv[6];
#pragma unroll
            for (int i = 0; i < 4; i++)
                af[i] = *(const bf16x8*)(&buf[swz64(i * 16 + l15, kb)]);
#pragma unroll
            for (int j = 0; j < 6; j++)
                bv[j] = *(const bf16x8*)(&Vb[swz64(w * 96 + j * 16 + l15, kb)]);
#pragma unroll
            for (int i = 0; i < 4; i++)
#pragma unroll
                for (int j = 0; j < 6; j++)
                    acc[i][j] = __builtin_amdgcn_mfma_f32_16x16x32_bf16(
                        af[i], bv[j], acc[i][j], 0, 0, 0);
        }

        // ---- epilogue: qp[c] += u[a,c] * (W[c][a]-Wl[a]), a in this at ----
        // C/D layout: col(c)=lane&15, row(a)=g*4+reg
#pragma unroll
        for (int i = 0; i < 4; i++) {
            const int a0 = at * 64 + i * 16 + g * 4;
            const float4 wle = *(const float4*)(Wl + a0);
#pragma unroll
            for (int j = 0; j < 6; j++) {
                const int c = w * 96 + j * 16 + l15;
                if (c < C_NUM) {
                    const float4 wv = *(const float4*)(W + (size_t)c * A_DIM + a0);
                    const f32x4 u = acc[i][j];
                    qp[j] += u[0] * (wv.x - wle.x) + u[1] * (wv.y - wle.y)
                           + u[2] * (wv.z - wle.z) + u[3] * (wv.w - wle.w);
                }
            }
        }

        // ---- convert + store the prefetched tile into the other buffer ----
        if (at < 7) {
#pragma unroll
            for (int p = 0; p < 4; p++) {
                const float4 s = pf[p];
                *(short4*)(&Sa[(at + 1) & 1][swz64(r0 + p * 16, c4 * 4)]) =
                    make_short4(f2bf(s.x), f2bf(s.y), f2bf(s.z), f2bf(s.w));
            }
        }
        __syncthreads();
    }

    // reduce the 4 g-groups (same c, different a rows), accumulate globally
#pragma unroll
    for (int j = 0; j < 6; j++) {
        float v = qp[j];
        v += __shfl_xor(v, 16);
        v += __shfl_xor(v, 32);
        if (g == 0) {
            const int c = w * 96 + j * 16 + l15;
            if (c < C_NUM) atomicAdd(&q2[(size_t)n * C_NUM + c], v);
        }
    }
}

// aug[c] = ys + 0.5*Lam*q2 + Lam*(w_c - w_l).dm ; nll = logsumexp - aug[l]
__global__ __launch_bounds__(256) void losskern(
    const float* __restrict__ W,
    const float* __restrict__ ys,
    const int*   __restrict__ labels,
    const float* __restrict__ lambda_p,
    const float* __restrict__ mean_s,
    const float* __restrict__ mean_t,
    const float* __restrict__ q2,
    float*       __restrict__ out)
{
    const int n = blockIdx.x;
    const int tid = threadIdx.x;
    const int lane = tid & 63;
    const int w = tid >> 6;
    const int l = labels[n];
    const float Lam = *lambda_p;

    __shared__ float aug[C_NUM];
    __shared__ float red[256];

    const int a0 = lane * 8;
    const float* Wl = W + (size_t)l * A_DIM;
    const float4 wl0 = *(const float4*)(Wl + a0);
    const float4 wl1 = *(const float4*)(Wl + a0 + 4);
    const float4 mt0 = *(const float4*)(mean_t + (size_t)l * A_DIM + a0);
    const float4 mt1 = *(const float4*)(mean_t + (size_t)l * A_DIM + a0 + 4);
    const float4 ms0 = *(const float4*)(mean_s + (size_t)l * A_DIM + a0);
    const float4 ms1 = *(const float4*)(mean_s + (size_t)l * A_DIM + a0 + 4);
    const float dm0 = mt0.x - ms0.x, dm1 = mt0.y - ms0.y, dm2 = mt0.z - ms0.z, dm3 = mt0.w - ms0.w;
    const float dm4 = mt1.x - ms1.x, dm5 = mt1.y - ms1.y, dm6 = mt1.z - ms1.z, dm7 = mt1.w - ms1.w;
    const float wldm = wl0.x*dm0 + wl0.y*dm1 + wl0.z*dm2 + wl0.w*dm3
                     + wl1.x*dm4 + wl1.y*dm5 + wl1.z*dm6 + wl1.w*dm7;

    for (int c = w; c < C_NUM; c += 4) {
        const float* Wc = W + (size_t)c * A_DIM;
        const float4 w0 = *(const float4*)(Wc + a0);
        const float4 w1 = *(const float4*)(Wc + a0 + 4);
        float d = w0.x*dm0 + w0.y*dm1 + w0.z*dm2 + w0.w*dm3
                + w1.x*dm4 + w1.y*dm5 + w1.z*dm6 + w1.w*dm7 - wldm;
        d += __shfl_xor(d, 1);
        d += __shfl_xor(d, 2);
        d += __shfl_xor(d, 4);
        d += __shfl_xor(d, 8);
        d += __shfl_xor(d, 16);
        d += __shfl_xor(d, 32);
        if (lane == 0)
            aug[c] = ys[(size_t)n * C_NUM + c] + 0.5f * Lam * q2[(size_t)n * C_NUM + c] + Lam * d;
    }
    __syncthreads();

    float m = -INFINITY;
    for (int c = tid; c < C_NUM; c += 256) m = fmaxf(m, aug[c]);
    red[tid] = m;
    __syncthreads();
    for (int s = 128; s > 0; s >>= 1) {
        if (tid < s) red[tid] = fmaxf(red[tid], red[tid + s]);
        __syncthreads();
    }
    m = red[0];
    __syncthreads();

    float se = 0.f;
    for (int c = tid; c < C_NUM; c += 256) se += expf(aug[c] - m);
    red[tid] = se;
    __syncthreads();
    for (int s = 128; s > 0; s >>= 1) {
        if (tid < s) red[tid] += red[tid + s];
        __syncthreads();
    }
    if (tid == 0) {
        const float logZ = m + logf(red[0]);
        atomicAdd(out, (logZ - aug[l]) * (1.f / (float)N_NUM));
    }
}

extern "C" void kernel_launch(void* const* d_in, const int* in_sizes, int n_in,
                              void* d_out, int out_size, void* d_ws, size_t ws_size,
                              hipStream_t stream) {
    const float* W      = (const float*)d_in[0];
    // d_in[1] = features_source: unused by the reference.
    const float* ys     = (const float*)d_in[2];
    const int*   labels = (const int*)d_in[3];
    const float* lam    = (const float*)d_in[4];
    const float* means  = (const float*)d_in[5];
    const float* meant  = (const float*)d_in[6];
    const float* cov    = (const float*)d_in[7];
    float* out = (float*)d_out;
    float* q2  = (float*)d_ws;   // N*C floats = 706,560 B

    hipMemsetAsync(q2, 0, (size_t)N_NUM * C_NUM * sizeof(float), stream);
    hipMemsetAsync(out, 0, sizeof(float), stream);

    qkern<<<dim3(NBB, N_NUM), 256, 0, stream>>>(W, labels, cov, q2);
    losskern<<<N_NUM, 256, 0, stream>>>(W, ys, labels, lam, means, meant, q2, out);
}